// Round 6
// baseline (3148.226 us; speedup 1.0000x reference)
//
#include <hip/hip_runtime.h>
#include <math.h>

typedef unsigned short u16;
typedef __attribute__((ext_vector_type(8))) short bf8_t;   // 8 bf16 (4 VGPR)
typedef __attribute__((ext_vector_type(4))) float f4_t;    // 4 fp32

#define BB 256
#define LL 200
#define HH 256
#define EE 512
#define NSTATE 16
#define KCONV 4
#define RR 16
#define NLAYER 2
#define VV 150000
#define TT 300
#define MTOK (BB*TT)      // 76800
#define NC 8              // scan chunks
#define CL 38             // chunk length (8*38=304 >= 300)

#define LOG2E 1.44269504088896340736f
#define LN2   0.69314718055994530942f

// ---------------------------------------------------------------------------
// helpers
// ---------------------------------------------------------------------------
__device__ __forceinline__ float siluf(float x) { return x / (1.0f + expf(-x)); }
__device__ __forceinline__ float geluf(float x) {
    return 0.5f * x * (1.0f + erff(x * 0.70710678118654752440f));
}
__device__ __forceinline__ u16 f2bf(float x) {               // RNE float->bf16
    unsigned u = __float_as_uint(x);
    unsigned r = u + 0x7FFF + ((u >> 16) & 1);
    return (u16)(r >> 16);
}
__device__ __forceinline__ float bf2f(u16 b) { return __uint_as_float((unsigned)b << 16); }

__device__ __forceinline__ void gload16(const void* gp, void* lp) {
    __builtin_amdgcn_global_load_lds(
        (const __attribute__((address_space(1))) unsigned int*)gp,
        (__attribute__((address_space(3))) unsigned int*)lp,
        16, 0, 0);
}

__device__ __forceinline__ void block_reduce2(float& a, float& b) {
    __shared__ float ra[4], rb[4];
    #pragma unroll
    for (int o = 32; o > 0; o >>= 1) {
        a += __shfl_down(a, o, 64);
        b += __shfl_down(b, o, 64);
    }
    int lane = threadIdx.x & 63, w = threadIdx.x >> 6;
    if (lane == 0) { ra[w] = a; rb[w] = b; }
    __syncthreads();
    a = ra[0] + ra[1] + ra[2] + ra[3];
    b = rb[0] + rb[1] + rb[2] + rb[3];
}

// ---------------------------------------------------------------------------
// split a fp32 tensor into bf16 hi/lo planes
// ---------------------------------------------------------------------------
__global__ __launch_bounds__(256)
void split_kernel(const float* __restrict__ x, u16* __restrict__ ph,
                  u16* __restrict__ pl, int n) {
    int i = blockIdx.x * 256 + threadIdx.x;
    if (i < n) {
        float v = x[i];
        u16 hb = f2bf(v);
        ph[i] = hb;
        pl[i] = f2bf(v - bf2f(hb));
    }
}

// ---------------------------------------------------------------------------
// 1. embedding gather + LayerNorm -> hi/lo planes of h
// ---------------------------------------------------------------------------
__global__ __launch_bounds__(256)
void embed_ln_kernel(const int* __restrict__ item_seq,
                     const float* __restrict__ item_emb,
                     const float* __restrict__ ln_w,
                     const float* __restrict__ ln_b,
                     u16* __restrict__ hh, u16* __restrict__ hl) {
    int tok = blockIdx.x;
    int b = tok / TT, p = tok - b * TT;
    int k = p / 3, r = p - 3 * k;
    int item;
    if (r == 2) item = VV - 1;
    else        item = item_seq[b * LL + 2 * k + r];
    int tid = threadIdx.x;
    float x = item_emb[(size_t)item * HH + tid];
    float s1 = x, s2 = x * x;
    block_reduce2(s1, s2);
    float m = s1 * (1.0f / HH);
    float var = s2 * (1.0f / HH) - m * m;
    float inv = rsqrtf(var + 1e-12f);
    float v = (x - m) * inv * ln_w[tid] + ln_b[tid];
    size_t idx = (size_t)tok * HH + tid;
    u16 hb = f2bf(v);
    hh[idx] = hb;
    hl[idx] = f2bf(v - bf2f(hb));
}

// ---------------------------------------------------------------------------
// 2. residual add + LayerNorm on the plane residual stream
// ---------------------------------------------------------------------------
__global__ __launch_bounds__(256)
void add_ln_kernel(const float* __restrict__ tmp,
                   u16* __restrict__ hh, u16* __restrict__ hl,
                   const float* __restrict__ w,
                   const float* __restrict__ bnorm) {
    int tok = blockIdx.x;
    int tid = threadIdx.x;
    size_t idx = (size_t)tok * HH + tid;
    float x = tmp[idx] + bf2f(hh[idx]) + bf2f(hl[idx]);
    float s1 = x, s2 = x * x;
    block_reduce2(s1, s2);
    float m = s1 * (1.0f / HH);
    float var = s2 * (1.0f / HH) - m * m;
    float inv = rsqrtf(var + 1e-12f);
    float v = (x - m) * inv * w[tid] + bnorm[tid];
    u16 hb = f2bf(v);
    hh[idx] = hb;
    hl[idx] = f2bf(v - bf2f(hb));
}

// ---------------------------------------------------------------------------
// 3. split-bf16 MFMA GEMM: C[M,N] = A[M,K] @ W[N,K]^T (+bias)
//    AMODE 0: A = bf16 hi/lo planes (lda=K) via global_load_lds
//    AMODE 1: A = fp32 rows (lda=ldaf): u = y*silu(z at +EE), reg split
//    AMODE 2: A = fp32 rows (lda=ldaf): plain, reg split
//    MODE 0: fp32 C (+bias).  MODE 1: gelu(C+bias) -> hi/lo planes
// ---------------------------------------------------------------------------
template <int AMODE, int MODE>
__global__ __launch_bounds__(256)
void gemm_mfma(const u16* __restrict__ Ah, const u16* __restrict__ Al,
               const float* __restrict__ Af, int ldaf,
               const u16* __restrict__ Wh, const u16* __restrict__ Wl,
               const float* __restrict__ bias,
               float* __restrict__ C,
               u16* __restrict__ Ch, u16* __restrict__ Cl,
               int M, int N, int K) {
    __shared__ u16 sA[2][128 * 32];
    __shared__ u16 sB[2][128 * 32];
    int tid = threadIdx.x;
    int lane = tid & 63, wid = tid >> 6;
    int wr = wid >> 1, wc = wid & 1;

    // XCD-aware bijective swizzle (m204)
    int gx = gridDim.x, nwg = gx * gridDim.y;
    int id = blockIdx.y * gx + blockIdx.x;
    int q = nwg >> 3, rr8 = nwg & 7;
    int xcd = id & 7, pos = id >> 3;
    int nid = (xcd < rr8 ? xcd * (q + 1) : rr8 * (q + 1) + (xcd - rr8) * q) + pos;
    int bn = (nid % gx) * 128;
    int bm = (nid / gx) * 128;

    f4_t acc[4][4];
    #pragma unroll
    for (int i = 0; i < 4; ++i)
        #pragma unroll
        for (int j = 0; j < 4; ++j)
            acc[i][j] = (f4_t){0.f, 0.f, 0.f, 0.f};

    int scol = (lane & 3) * 8;

    for (int k0 = 0; k0 < K; k0 += 32) {
        if (AMODE == 0) {
            #pragma unroll
            for (int qq = 0; qq < 2; ++qq) {
                int row = wid * 32 + qq * 16 + (lane >> 2);
                size_t ga = (size_t)(bm + row) * K + k0 + scol;
                int off = (wid * 2 + qq) * 1024;
                gload16(Ah + ga, (char*)&sA[0][0] + off);
                gload16(Al + ga, (char*)&sA[1][0] + off);
            }
        } else {
            int r = tid >> 1;
            int kc = (tid & 1) * 16;
            size_t base = (size_t)(bm + r) * ldaf + k0 + kc;
            float us[16];
            #pragma unroll
            for (int i = 0; i < 16; i += 4) {
                float4 y4 = *(const float4*)(Af + base + i);
                if (AMODE == 1) {
                    float4 z4 = *(const float4*)(Af + base + EE + i);
                    us[i + 0] = y4.x * (z4.x / (1.f + __expf(-z4.x)));
                    us[i + 1] = y4.y * (z4.y / (1.f + __expf(-z4.y)));
                    us[i + 2] = y4.z * (z4.z / (1.f + __expf(-z4.z)));
                    us[i + 3] = y4.w * (z4.w / (1.f + __expf(-z4.w)));
                } else {
                    us[i + 0] = y4.x; us[i + 1] = y4.y;
                    us[i + 2] = y4.z; us[i + 3] = y4.w;
                }
            }
            alignas(16) u16 hb[16], lb[16];
            #pragma unroll
            for (int i = 0; i < 16; ++i) {
                hb[i] = f2bf(us[i]);
                lb[i] = f2bf(us[i] - bf2f(hb[i]));
            }
            *(bf8_t*)&sA[0][r * 32 + kc]     = *(bf8_t*)&hb[0];
            *(bf8_t*)&sA[0][r * 32 + kc + 8] = *(bf8_t*)&hb[8];
            *(bf8_t*)&sA[1][r * 32 + kc]     = *(bf8_t*)&lb[0];
            *(bf8_t*)&sA[1][r * 32 + kc + 8] = *(bf8_t*)&lb[8];
        }
        #pragma unroll
        for (int qq = 0; qq < 2; ++qq) {
            int row = wid * 32 + qq * 16 + (lane >> 2);
            size_t gb = (size_t)(bn + row) * K + k0 + scol;
            int off = (wid * 2 + qq) * 1024;
            gload16(Wh + gb, (char*)&sB[0][0] + off);
            gload16(Wl + gb, (char*)&sB[1][0] + off);
        }
        __syncthreads();

        int arow = wr * 64 + (lane & 15);
        int koff = (lane >> 4) * 8;
        bf8_t ah[4], al[4];
        #pragma unroll
        for (int fm = 0; fm < 4; ++fm) {
            int r = arow + fm * 16;
            ah[fm] = *(const bf8_t*)&sA[0][r * 32 + koff];
            al[fm] = *(const bf8_t*)&sA[1][r * 32 + koff];
        }
        #pragma unroll
        for (int fn = 0; fn < 4; ++fn) {
            int r = wc * 64 + fn * 16 + (lane & 15);
            bf8_t bh = *(const bf8_t*)&sB[0][r * 32 + koff];
            bf8_t bl = *(const bf8_t*)&sB[1][r * 32 + koff];
            #pragma unroll
            for (int fm = 0; fm < 4; ++fm) {
                acc[fm][fn] = __builtin_amdgcn_mfma_f32_16x16x32_bf16(ah[fm], bh, acc[fm][fn], 0, 0, 0);
                acc[fm][fn] = __builtin_amdgcn_mfma_f32_16x16x32_bf16(ah[fm], bl, acc[fm][fn], 0, 0, 0);
                acc[fm][fn] = __builtin_amdgcn_mfma_f32_16x16x32_bf16(al[fm], bh, acc[fm][fn], 0, 0, 0);
            }
        }
        __syncthreads();
    }

    #pragma unroll
    for (int fn = 0; fn < 4; ++fn) {
        int colg = bn + wc * 64 + fn * 16 + (lane & 15);
        if (colg < N) {
            float bv = (bias != nullptr) ? bias[colg] : 0.f;
            #pragma unroll
            for (int fm = 0; fm < 4; ++fm) {
                #pragma unroll
                for (int j = 0; j < 4; ++j) {
                    int rowg = bm + wr * 64 + fm * 16 + (lane >> 4) * 4 + j;
                    float v = acc[fm][fn][j] + bv;
                    if (MODE == 0) {
                        C[(size_t)rowg * N + colg] = v;
                    } else {
                        v = geluf(v);
                        u16 hbv = f2bf(v);
                        Ch[(size_t)rowg * N + colg] = hbv;
                        Cl[(size_t)rowg * N + colg] = f2bf(v - bf2f(hbv));
                    }
                }
            }
        }
    }
}

// ---------------------------------------------------------------------------
// 3b. narrow x_proj GEMM: xdbl[M,48] = xc[M,K=512] @ W[48,512]^T
// ---------------------------------------------------------------------------
__global__ __launch_bounds__(256)
void gemm_xproj(const float* __restrict__ Af,          // xz rows, lda = 2E
                const u16* __restrict__ Wh, const u16* __restrict__ Wl,
                float* __restrict__ C) {               // ldc = 48
    __shared__ u16 sA[2][128 * 32];
    __shared__ u16 sB[2][48 * 32];
    int tid = threadIdx.x;
    int lane = tid & 63, wid = tid >> 6;
    int bm = blockIdx.x * 128;

    f4_t acc[2][3];
    #pragma unroll
    for (int i = 0; i < 2; ++i)
        #pragma unroll
        for (int j = 0; j < 3; ++j)
            acc[i][j] = (f4_t){0.f, 0.f, 0.f, 0.f};

    for (int k0 = 0; k0 < EE; k0 += 32) {
        {
            int r = tid >> 1;
            int kc = (tid & 1) * 16;
            size_t base = (size_t)(bm + r) * (2 * EE) + k0 + kc;
            float us[16];
            #pragma unroll
            for (int i = 0; i < 16; i += 4) {
                float4 y4 = *(const float4*)(Af + base + i);
                us[i + 0] = y4.x; us[i + 1] = y4.y;
                us[i + 2] = y4.z; us[i + 3] = y4.w;
            }
            alignas(16) u16 hb[16], lb[16];
            #pragma unroll
            for (int i = 0; i < 16; ++i) {
                hb[i] = f2bf(us[i]);
                lb[i] = f2bf(us[i] - bf2f(hb[i]));
            }
            *(bf8_t*)&sA[0][r * 32 + kc]     = *(bf8_t*)&hb[0];
            *(bf8_t*)&sA[0][r * 32 + kc + 8] = *(bf8_t*)&hb[8];
            *(bf8_t*)&sA[1][r * 32 + kc]     = *(bf8_t*)&lb[0];
            *(bf8_t*)&sA[1][r * 32 + kc + 8] = *(bf8_t*)&lb[8];
        }
        if (tid < 192) {
            int row = tid >> 2;
            int c16 = (tid & 3) * 8;
            size_t gb = (size_t)row * EE + k0 + c16;
            gload16(Wh + gb, (char*)&sB[0][0] + tid * 16);
            gload16(Wl + gb, (char*)&sB[1][0] + tid * 16);
        }
        __syncthreads();

        int arow = wid * 32 + (lane & 15);
        int koff = (lane >> 4) * 8;
        bf8_t ah[2], al[2];
        #pragma unroll
        for (int fm = 0; fm < 2; ++fm) {
            int r = arow + fm * 16;
            ah[fm] = *(const bf8_t*)&sA[0][r * 32 + koff];
            al[fm] = *(const bf8_t*)&sA[1][r * 32 + koff];
        }
        #pragma unroll
        for (int fn = 0; fn < 3; ++fn) {
            int r = fn * 16 + (lane & 15);
            bf8_t bh = *(const bf8_t*)&sB[0][r * 32 + koff];
            bf8_t bl = *(const bf8_t*)&sB[1][r * 32 + koff];
            #pragma unroll
            for (int fm = 0; fm < 2; ++fm) {
                acc[fm][fn] = __builtin_amdgcn_mfma_f32_16x16x32_bf16(ah[fm], bh, acc[fm][fn], 0, 0, 0);
                acc[fm][fn] = __builtin_amdgcn_mfma_f32_16x16x32_bf16(ah[fm], bl, acc[fm][fn], 0, 0, 0);
                acc[fm][fn] = __builtin_amdgcn_mfma_f32_16x16x32_bf16(al[fm], bh, acc[fm][fn], 0, 0, 0);
            }
        }
        __syncthreads();
    }

    #pragma unroll
    for (int fn = 0; fn < 3; ++fn) {
        int colg = fn * 16 + (lane & 15);
        #pragma unroll
        for (int fm = 0; fm < 2; ++fm) {
            #pragma unroll
            for (int j = 0; j < 4; ++j) {
                int rowg = bm + wid * 32 + fm * 16 + (lane >> 4) * 4 + j;
                C[(size_t)rowg * 48 + colg] = acc[fm][fn][j];
            }
        }
    }
}

// ---------------------------------------------------------------------------
// 4a. conv halo snapshot: save x[t0-3..t0-1] per (b,e,chunk) before in-place
// ---------------------------------------------------------------------------
__global__ __launch_bounds__(256)
void conv_halo_kernel(const float* __restrict__ xz, float* __restrict__ halo) {
    int g = blockIdx.x * 256 + threadIdx.x;       // b*NC*EE + c*EE + e
    int e = g & (EE - 1);
    int c = (g >> 9) & (NC - 1);
    int b = g >> 12;
    int t0 = c * CL;
    const float* xp = xz + (size_t)b * TT * (2 * EE) + e;
    float* hp = halo + (((size_t)b * NC + c) * 3) * EE + e;
    #pragma unroll
    for (int k = 0; k < 3; ++k) {
        int t = t0 - 3 + k;
        hp[(size_t)k * EE] = (t >= 0) ? xp[(size_t)t * (2 * EE)] : 0.f;
    }
}

// ---------------------------------------------------------------------------
// 4b. chunked causal depthwise conv (K=4) + bias + SiLU, in place
// ---------------------------------------------------------------------------
__global__ __launch_bounds__(256)
void conv_chunk_kernel(float* __restrict__ xz, const float* __restrict__ halo,
                       const float* __restrict__ conv_w,
                       const float* __restrict__ conv_b, int layer) {
    int g = blockIdx.x * 256 + threadIdx.x;
    int e = g & (EE - 1);
    int c = (g >> 9) & (NC - 1);
    int b = g >> 12;
    int t0 = c * CL, t1 = t0 + CL; if (t1 > TT) t1 = TT;
    int ns = t1 - t0;
    const float* w = conv_w + ((size_t)layer * EE + e) * KCONV;
    float w0 = w[0], w1 = w[1], w2 = w[2], w3 = w[3];
    float bias = conv_b[layer * EE + e];
    const float* hp = halo + (((size_t)b * NC + c) * 3) * EE + e;
    float h0 = hp[0], h1 = hp[(size_t)EE], h2 = hp[(size_t)2 * EE];
    float* p = xz + ((size_t)b * TT + t0) * (2 * EE) + e;
    for (int t = 0; t < ns; ++t) {
        float x3 = p[(size_t)t * (2 * EE)];
        float v = fmaf(w0, h0, fmaf(w1, h1, fmaf(w2, h2, fmaf(w3, x3, bias))));
        p[(size_t)t * (2 * EE)] = v / (1.f + __expf(-v));
        h0 = h1; h1 = h2; h2 = x3;
    }
}

// ---------------------------------------------------------------------------
// 5. chunked selective scan.
//    CHAIN: es_n = w^(n+1) (A_log = log(1..16) structure, device-verified)
//    EMIT:  pass3 — compute y, fuse u = y*silu(z), write in place
// ---------------------------------------------------------------------------
template <bool CHAIN, bool EMIT>
__device__ __forceinline__ void scan_chunk_body(
        int ns,
        const float* __restrict__ rowp,    // xdbl rows (48 f each)
        float* __restrict__ xp,            // x in / u out, stride 2E
        const float* __restrict__ zp,      // z, stride 2E (EMIT)
        const float* __restrict__ dw,      // 16
        float db, float A0,
        const float* __restrict__ arl2e,   // 16 (for !CHAIN)
        float Dv, float* __restrict__ s, float& dsum) {
    for (int t = 0; t < ns; ++t) {
        const float* row = rowp + (size_t)t * 48;
        float4 a0v = *(const float4*)(row + 0);
        float4 a1v = *(const float4*)(row + 4);
        float4 a2v = *(const float4*)(row + 8);
        float4 a3v = *(const float4*)(row + 12);
        float p0 = fmaf(a0v.w, dw[3],  fmaf(a0v.z, dw[2],  fmaf(a0v.y, dw[1],  a0v.x * dw[0])));
        float p1 = fmaf(a1v.w, dw[7],  fmaf(a1v.z, dw[6],  fmaf(a1v.y, dw[5],  a1v.x * dw[4])));
        float p2 = fmaf(a2v.w, dw[11], fmaf(a2v.z, dw[10], fmaf(a2v.y, dw[9],  a2v.x * dw[8])));
        float p3 = fmaf(a3v.w, dw[15], fmaf(a3v.z, dw[14], fmaf(a3v.y, dw[13], a3v.x * dw[12])));
        float rr = db + ((p0 + p1) + (p2 + p3));
        float qv = exp2f(-fabsf(rr) * LOG2E);
        float dt = fmaxf(rr, 0.f) + LN2 * __log2f(1.f + qv);
        if (!EMIT) dsum += dt;
        float xv = xp[(size_t)t * (2 * EE)];
        float dx = dt * xv;
        alignas(16) float Bv[16];
        *(float4*)&Bv[0]  = *(const float4*)(row + 16);
        *(float4*)&Bv[4]  = *(const float4*)(row + 20);
        *(float4*)&Bv[8]  = *(const float4*)(row + 24);
        *(float4*)&Bv[12] = *(const float4*)(row + 28);
        alignas(16) float Cv[16];
        if (EMIT) {
            *(float4*)&Cv[0]  = *(const float4*)(row + 32);
            *(float4*)&Cv[4]  = *(const float4*)(row + 36);
            *(float4*)&Cv[8]  = *(const float4*)(row + 40);
            *(float4*)&Cv[12] = *(const float4*)(row + 44);
        }
        float q[4] = {0.f, 0.f, 0.f, 0.f};
        if (CHAIN) {
            float w = exp2f(dt * A0);
            float wp = w;
            #pragma unroll
            for (int n = 0; n < 16; ++n) {
                if (n) wp *= w;
                s[n] = fmaf(s[n], wp, dx * Bv[n]);
                if (EMIT) q[n & 3] = fmaf(s[n], Cv[n], q[n & 3]);
            }
        } else {
            #pragma unroll
            for (int n = 0; n < 16; ++n) {
                float es = exp2f(dt * arl2e[n]);
                s[n] = fmaf(s[n], es, dx * Bv[n]);
                if (EMIT) q[n & 3] = fmaf(s[n], Cv[n], q[n & 3]);
            }
        }
        if (EMIT) {
            float y = ((q[0] + q[1]) + (q[2] + q[3])) + xv * Dv;
            float zv = zp[(size_t)t * (2 * EE)];
            float u = y * (zv / (1.f + __expf(-zv)));
            xp[(size_t)t * (2 * EE)] = u;
        }
    }
}

__device__ __forceinline__ void load_scan_params(
        const float* dt_w, const float* dt_b, const float* A_log,
        int layer, int e, float* dw, float& db, float& A0,
        float* arl2e, bool& chain) {
    #pragma unroll
    for (int i = 0; i < 16; i += 4)
        *(float4*)&dw[i] = *(const float4*)(dt_w + ((size_t)layer * EE + e) * RR + i);
    db = dt_b[layer * EE + e];
    const float* alp = A_log + ((size_t)layer * EE + e) * NSTATE;
    float ar[16];
    #pragma unroll
    for (int i = 0; i < 16; i += 4) {
        float4 v = *(const float4*)(alp + i);
        ar[i + 0] = -expf(v.x); ar[i + 1] = -expf(v.y);
        ar[i + 2] = -expf(v.z); ar[i + 3] = -expf(v.w);
    }
    chain = true;
    #pragma unroll
    for (int n = 1; n < 16; ++n)
        chain = chain && (fabsf(ar[n] - (n + 1) * ar[0]) <= 1e-3f * (n + 1) * fabsf(ar[0]));
    A0 = ar[0] * LOG2E;
    #pragma unroll
    for (int n = 0; n < 16; ++n) arl2e[n] = ar[n] * LOG2E;
}

__global__ __launch_bounds__(256, 4)
void scan_p1(const float* __restrict__ xdbl, float* __restrict__ xz,
             const float* __restrict__ dt_w, const float* __restrict__ dt_b,
             const float* __restrict__ A_log,
             float* __restrict__ SF, float* __restrict__ DS, int layer) {
    int g = blockIdx.x * 256 + threadIdx.x;
    int e = g & (EE - 1);
    int c = (g >> 9) & (NC - 1);
    int b = g >> 12;
    int t0 = c * CL, t1 = t0 + CL; if (t1 > TT) t1 = TT;
    alignas(16) float dw[16], arl2e[16];
    float db, A0; bool chain;
    load_scan_params(dt_w, dt_b, A_log, layer, e, dw, db, A0, arl2e, chain);

    const float* rowp = xdbl + ((size_t)b * TT + t0) * 48;
    float* xp = xz + ((size_t)b * TT + t0) * (2 * EE) + e;
    float s[16];
    #pragma unroll
    for (int n = 0; n < 16; ++n) s[n] = 0.f;
    float dsum = 0.f;
    int ns = t1 - t0;
    if (chain) scan_chunk_body<true, false>(ns, rowp, xp, nullptr, dw, db, A0, arl2e, 0.f, s, dsum);
    else       scan_chunk_body<false, false>(ns, rowp, xp, nullptr, dw, db, A0, arl2e, 0.f, s, dsum);
    size_t sbase = (((size_t)b * EE + e) * NC + c) * 16;
    #pragma unroll
    for (int i = 0; i < 16; i += 4) *(float4*)(SF + sbase + i) = *(float4*)&s[i];
    DS[((size_t)b * EE + e) * NC + c] = dsum;
}

__global__ __launch_bounds__(256)
void scan_p2(const float* __restrict__ A_log,
             float* __restrict__ SF, const float* __restrict__ DS, int layer) {
    int g = blockIdx.x * 256 + threadIdx.x;       // 0..B*E-1
    int e = g & (EE - 1), b = g >> 9;
    const float* alp = A_log + ((size_t)layer * EE + e) * NSTATE;
    float ar[16];
    #pragma unroll
    for (int i = 0; i < 16; i += 4) {
        float4 v = *(const float4*)(alp + i);
        ar[i + 0] = -expf(v.x); ar[i + 1] = -expf(v.y);
        ar[i + 2] = -expf(v.z); ar[i + 3] = -expf(v.w);
    }
    bool chain = true;
    #pragma unroll
    for (int n = 1; n < 16; ++n)
        chain = chain && (fabsf(ar[n] - (n + 1) * ar[0]) <= 1e-3f * (n + 1) * fabsf(ar[0]));
    float A0 = ar[0] * LOG2E;
    float arl2e[16];
    #pragma unroll
    for (int n = 0; n < 16; ++n) arl2e[n] = ar[n] * LOG2E;

    float s[16];
    #pragma unroll
    for (int n = 0; n < 16; ++n) s[n] = 0.f;
    size_t base = ((size_t)b * EE + e) * NC;
    for (int c = 0; c < NC; ++c) {
        float ds = DS[base + c];
        alignas(16) float f[16];
        #pragma unroll
        for (int i = 0; i < 16; i += 4) *(float4*)&f[i] = *(const float4*)(SF + (base + c) * 16 + i);
        #pragma unroll
        for (int i = 0; i < 16; i += 4) *(float4*)(SF + (base + c) * 16 + i) = *(float4*)&s[i];
        if (chain) {
            float w = exp2f(ds * A0), wp = w;
            #pragma unroll
            for (int n = 0; n < 16; ++n) { if (n) wp *= w; s[n] = fmaf(s[n], wp, f[n]); }
        } else {
            #pragma unroll
            for (int n = 0; n < 16; ++n) s[n] = fmaf(s[n], exp2f(ds * arl2e[n]), f[n]);
        }
    }
}

__global__ __launch_bounds__(256, 4)
void scan_p3(const float* __restrict__ xdbl, float* __restrict__ xz,
             const float* __restrict__ dt_w, const float* __restrict__ dt_b,
             const float* __restrict__ A_log, const float* __restrict__ Dp,
             const float* __restrict__ SF, int layer) {
    int g = blockIdx.x * 256 + threadIdx.x;
    int e = g & (EE - 1);
    int c = (g >> 9) & (NC - 1);
    int b = g >> 12;
    int t0 = c * CL, t1 = t0 + CL; if (t1 > TT) t1 = TT;
    alignas(16) float dw[16], arl2e[16];
    float db, A0; bool chain;
    load_scan_params(dt_w, dt_b, A_log, layer, e, dw, db, A0, arl2e, chain);
    float Dv = Dp[layer * EE + e];

    const float* rowp = xdbl + ((size_t)b * TT + t0) * 48;
    float* xp = xz + ((size_t)b * TT + t0) * (2 * EE) + e;
    const float* zp = xp + EE;
    float s[16];
    size_t sbase = (((size_t)b * EE + e) * NC + c) * 16;
    #pragma unroll
    for (int i = 0; i < 16; i += 4) *(float4*)&s[i] = *(const float4*)(SF + sbase + i);
    float dsum = 0.f;
    int ns = t1 - t0;
    if (chain) scan_chunk_body<true, true>(ns, rowp, xp, zp, dw, db, A0, arl2e, Dv, s, dsum);
    else       scan_chunk_body<false, true>(ns, rowp, xp, zp, dw, db, A0, arl2e, Dv, s, dsum);
}

// ---------------------------------------------------------------------------
// 6. final gather
// ---------------------------------------------------------------------------
__global__ __launch_bounds__(256)
void gather_out_kernel(const u16* __restrict__ hh, const u16* __restrict__ hl,
                       const int* __restrict__ seq_len,
                       float* __restrict__ out) {
    int b = blockIdx.x;
    int sl = seq_len[b];
    int tl = sl + sl / 2;
    int idx = tl - 1;
    if (idx < 0) idx = 0;
    if (idx > TT - 1) idx = TT - 1;
    size_t src = ((size_t)b * TT + idx) * HH + threadIdx.x;
    out[(size_t)b * HH + threadIdx.x] = bf2f(hh[src]) + bf2f(hl[src]);
}

// ---------------------------------------------------------------------------
// launch
// ---------------------------------------------------------------------------
extern "C" void kernel_launch(void* const* d_in, const int* in_sizes, int n_in,
                              void* d_out, int out_size, void* d_ws, size_t ws_size,
                              hipStream_t stream) {
    const int*   item_seq  = (const int*)  d_in[0];
    const int*   seq_len   = (const int*)  d_in[1];
    const float* item_emb  = (const float*)d_in[2];
    const float* ln_w      = (const float*)d_in[3];
    const float* ln_b      = (const float*)d_in[4];
    const float* in_proj_w = (const float*)d_in[5];
    const float* conv_w    = (const float*)d_in[6];
    const float* conv_b    = (const float*)d_in[7];
    const float* x_proj_w  = (const float*)d_in[8];
    const float* dt_w      = (const float*)d_in[9];
    const float* dt_b      = (const float*)d_in[10];
    const float* A_log     = (const float*)d_in[11];
    const float* Dp        = (const float*)d_in[12];
    const float* out_w     = (const float*)d_in[13];
    const float* mn_w      = (const float*)d_in[14];
    const float* mn_b      = (const float*)d_in[15];
    const float* fc1_w     = (const float*)d_in[16];
    const float* fc1_b     = (const float*)d_in[17];
    const float* fc2_w     = (const float*)d_in[18];
    const float* fc2_b     = (const float*)d_in[19];
    const float* fn_w      = (const float*)d_in[20];
    const float* fn_b      = (const float*)d_in[21];

    // ---- workspace layout: EXACTLY 486,604,800 B (round-1 proven size) ----
    float* xz   = (float*)d_ws;                       // MTOK*2E f   = 314,572,800 B
    u16*   hh   = (u16*)(xz + (size_t)MTOK * 2 * EE); // MTOK*H u16  =  39,321,600 B
    u16*   hl   = hh + (size_t)MTOK * HH;             //                39,321,600 B
    float* tmp  = (float*)(hl + (size_t)MTOK * HH);   // MTOK*H f    =  78,643,200 B
    float* xdbl = tmp + (size_t)MTOK * HH;            // MTOK*48 f   =  14,745,600 B
    // aliases of tmp (sequentially disjoint live ranges):
    float* halo = tmp;                                // B*NC*3*E f  = 12.6 MB
    u16* wsBH = (u16*)tmp;                            // x_proj planes
    u16* wsBL = wsBH + 24576;
    float* SF = tmp;                                  // B*E*NC*16 f = 67.1 MB
    float* DS = tmp + (size_t)16777216;               // B*E*NC f    =  4.2 MB
    // aliases of xdbl:
    u16* wsH = (u16*)xdbl;                            // big weight planes
    u16* wsL = wsH + 262144;
    // fc1 output planes alias xz:
    u16* ffh = (u16*)xz;
    u16* ffl = ffh + (size_t)MTOK * 4 * HH;

    embed_ln_kernel<<<MTOK, 256, 0, stream>>>(item_seq, item_emb, ln_w, ln_b, hh, hl);

    const int gscan = (BB * EE * NC) / 256;           // 4096 blocks

    for (int l = 0; l < NLAYER; ++l) {
        // in_proj: xz = h @ in_proj_w[l]^T   (M x 1024, K=256)
        {
            int nw = 2 * EE * HH;
            split_kernel<<<nw / 256, 256, 0, stream>>>(
                in_proj_w + (size_t)l * nw, wsH, wsL, nw);
            dim3 grid((2 * EE) / 128, MTOK / 128);
            gemm_mfma<0, 0><<<grid, 256, 0, stream>>>(
                hh, hl, nullptr, 0, wsH, wsL,
                nullptr, xz, nullptr, nullptr, MTOK, 2 * EE, HH);
        }
        // chunked conv (halo snapshot first, then in-place FIR+SiLU)
        conv_halo_kernel<<<gscan, 256, 0, stream>>>(xz, halo);
        conv_chunk_kernel<<<gscan, 256, 0, stream>>>(xz, halo, conv_w, conv_b, l);
        // x_proj (narrow MFMA, N=48, K=512)
        {
            int nw = 48 * EE;
            split_kernel<<<nw / 256, 256, 0, stream>>>(
                x_proj_w + (size_t)l * nw, wsBH, wsBL, nw);
            gemm_xproj<<<MTOK / 128, 256, 0, stream>>>(xz, wsBH, wsBL, xdbl);
        }
        // chunked selective scan; p3 writes u = y*silu(z) in place over xc
        scan_p1<<<gscan, 256, 0, stream>>>(xdbl, xz, dt_w, dt_b, A_log, SF, DS, l);
        scan_p2<<<(BB * EE) / 256, 256, 0, stream>>>(A_log, SF, DS, l);
        scan_p3<<<gscan, 256, 0, stream>>>(xdbl, xz, dt_w, dt_b, A_log, Dp, SF, l);
        // out proj: tmp = u @ out_w[l]^T   (M x 256, K=512)
        {
            int nw = HH * EE;
            split_kernel<<<nw / 256, 256, 0, stream>>>(
                out_w + (size_t)l * nw, wsH, wsL, nw);
            dim3 grid(HH / 128, MTOK / 128);
            gemm_mfma<2, 0><<<grid, 256, 0, stream>>>(
                nullptr, nullptr, xz, 2 * EE, wsH, wsL,
                nullptr, tmp, nullptr, nullptr, MTOK, HH, EE);
        }
        add_ln_kernel<<<MTOK, 256, 0, stream>>>(tmp, hh, hl, mn_w + l * HH, mn_b + l * HH);
        // fc1 + GELU
        {
            int nw = 4 * HH * HH;
            split_kernel<<<nw / 256, 256, 0, stream>>>(
                fc1_w + (size_t)l * nw, wsH, wsL, nw);
            dim3 grid((4 * HH) / 128, MTOK / 128);
            gemm_mfma<0, 1><<<grid, 256, 0, stream>>>(
                hh, hl, nullptr, 0, wsH, wsL,
                fc1_b + (size_t)l * 4 * HH,
                nullptr, ffh, ffl, MTOK, 4 * HH, HH);
        }
        // fc2
        {
            int nw = HH * 4 * HH;
            split_kernel<<<nw / 256, 256, 0, stream>>>(
                fc2_w + (size_t)l * nw, wsH, wsL, nw);
            dim3 grid(HH / 128, MTOK / 128);
            gemm_mfma<0, 0><<<grid, 256, 0, stream>>>(
                ffh, ffl, nullptr, 0, wsH, wsL,
                fc2_b + (size_t)l * HH,
                tmp, nullptr, nullptr, MTOK, HH, 4 * HH);
        }
        add_ln_kernel<<<MTOK, 256, 0, stream>>>(tmp, hh, hl, fn_w + l * HH, fn_b + l * HH);
    }

    gather_out_kernel<<<BB, 256, 0, stream>>>(hh, hl, seq_len, (float*)d_out);
}